// Round 15
// baseline (159.734 us; speedup 1.0000x reference)
//
#include <hip/hip_runtime.h>
#include <math.h>

#define ALPHA 0.2f
#define NP 50000
#define NA 25000
#define NBINS 150000          // P: 2*NP interleaved bins, then A: 2*NA
#define ABASE 100000          // bin base for A nodes
#define NBUCK 586             // ceil(NBINS/256)
#define CH 4096               // edges per scatter block (= 16*256, static unroll)
#define CAP 8192              // fixed bucket region capacity in ebuf (max observed ~3.9k)
#define GP ((NP + 63) / 64)   // 782 xform-P blocks
#define GA ((NA + 63) / 64)   // 391 xform-A blocks
#define XS_LD 68              // padded X-tile row stride (floats)

typedef unsigned short u16;
typedef __attribute__((ext_vector_type(8))) short bf16x8;
typedef __attribute__((ext_vector_type(8))) unsigned short u16x8;
typedef __attribute__((ext_vector_type(4))) float f32x4;

__device__ __forceinline__ float bf2f(u16 u) { return __uint_as_float(((unsigned)u) << 16); }
__device__ __forceinline__ u16 f2bf(float f) {
    unsigned x = __float_as_uint(f);
    return (u16)((x + 0x7fffu + ((x >> 16) & 1u)) >> 16);   // RNE
}

// =============== args ===============
struct FrontArgs {
    const float *feat_P, *feat_A, *feat_S;
    const float *W_P, *b_P, *W_A, *b_A, *W_p2p, *b_p2p, *W_p2a, *b_p2a,
                *W_a2p, *b_a2p, *W_a2a, *b_a2a, *W_p2s, *b_p2s, *W_a2s, *b_a2s,
                *W_in, *b_in;
    const float *a_p2p, *a_p2a, *a_a2p, *a_a2a, *a_p2s, *a_a2s;
    float *WhP, *WhA;
    u16 *z_p2p, *z_p2a, *z_a2p, *z_a2a;
    float *ss_p2p, *sd_p2p, *ss_p2a, *sd_p2a, *ss_a2p, *sd_a2p, *ss_a2a, *sd_a2a;
    float *outS, *den2, *numP, *numA;
    // scatter role:
    const int *src_p2p, *dst_p2p, *src_a2p, *dst_a2p,
              *src_p2a, *dst_p2a, *src_a2a, *dst_a2a;
    int E_p2p, E_a2p, E_p2a, E_a2a, E_tot, nblk;
    int *cursor0, *ebuf;
};

// =============== MFMA 4-matrix transform + fused state GAT partials ===============
// Waves 0..2: self/Wh + two edge-type z's (writes). Wave 3: state-message matrix
// (p2s or a2s) -- NO global z/ss writes; instead accumulates softmax num/den
// partials directly from registers (src list is arange -> every row contributes).
__device__ __forceinline__ void xform_body(int bid, float* __restrict__ Xs,
    const float* __restrict__ X, int N,
    const float* __restrict__ W0, const float* __restrict__ b0, float* __restrict__ Wh,
    const float* __restrict__ dA, float* __restrict__ sdA,
    const float* __restrict__ dB, float* __restrict__ sdB,
    const float* __restrict__ W1, const float* __restrict__ b1, u16* __restrict__ z1,
    const float* __restrict__ v1, float* __restrict__ s1,
    const float* __restrict__ W2, const float* __restrict__ b2, u16* __restrict__ z2,
    const float* __restrict__ v2, float* __restrict__ s2,
    const float* __restrict__ W3, const float* __restrict__ b3,
    const float* __restrict__ v3,                  // a_state src-half
    const float* __restrict__ aD,                  // a_state dst-half (64)
    const float* __restrict__ fS, const float* __restrict__ W_in, const float* __restrict__ b_in,
    float* __restrict__ num, float* __restrict__ den)
{
    int tid = threadIdx.x, wv = tid >> 6, lane = tid & 63;
    int g = lane >> 4, li = lane & 15;
    const float* Wm = wv == 0 ? W0 : wv == 1 ? W1 : wv == 2 ? W2 : W3;
    const float* bm = wv == 0 ? b0 : wv == 1 ? b1 : wv == 2 ? b2 : b3;
    const float* dv = wv == 0 ? dA : wv == 1 ? v1 : wv == 2 ? v2 : v3;
    float* sm       = wv == 0 ? sdA : wv == 1 ? s1 : wv == 2 ? s2 : nullptr;
    u16* zm         = wv == 1 ? z1 : wv == 2 ? z2 : nullptr;

    int base0 = bid * 64;
    // ---- stage X tile (64x64) once per block ----
    for (int i = tid; i < 4096; i += 256) {
        int r = i >> 6, c = i & 63;
        int rowC = min(base0 + r, N - 1);
        Xs[r * XS_LD + c] = X[(long long)rowC * 64 + c];
    }

    bf16x8 Bf[4][2];
#pragma unroll
    for (int cb = 0; cb < 4; ++cb)
#pragma unroll
        for (int kc = 0; kc < 2; ++kc) {
            bf16x8 t;
#pragma unroll
            for (int j = 0; j < 8; ++j)
                t[j] = (short)f2bf(Wm[(kc * 32 + g * 8 + j) * 64 + cb * 16 + li]);
            Bf[cb][kc] = t;
        }
    float bl[4], dvl[4], dbl[4];
#pragma unroll
    for (int cb = 0; cb < 4; ++cb) {
        bl[cb]  = bm[cb * 16 + li];
        dvl[cb] = dv[cb * 16 + li];
        dbl[cb] = (wv == 0) ? dB[cb * 16 + li] : 0.f;
    }
    // ---- wave 3: local sdst = dot(Wh_in, a_state_dst) (redundant per block, cheap) ----
    float sdst = 0.f;
    if (wv == 3) {
#pragma unroll
        for (int cb = 0; cb < 4; ++cb) {
            int c = cb * 16 + li;
            float a = b_in[c];
            for (int k = 0; k < 64; ++k) a = fmaf(fS[k], W_in[k * 64 + c], a);
            sdst = fmaf(a, aD[c], sdst);
        }
#pragma unroll
        for (int o = 1; o < 16; o <<= 1) sdst += __shfl_xor(sdst, o, 64);
    }
    float pnum[4] = {0.f, 0.f, 0.f, 0.f};
    float pden = 0.f;
    __syncthreads();                           // X tile ready

#pragma unroll
    for (int rt = 0; rt < 4; ++rt) {
        int rbase = base0 + rt * 16;
        if (rbase >= N) break;
        bf16x8 Af[2];
#pragma unroll
        for (int kc = 0; kc < 2; ++kc) {
            const float* xp = &Xs[(rt * 16 + li) * XS_LD + kc * 32 + g * 8];
            bf16x8 t;
#pragma unroll
            for (int j = 0; j < 8; ++j)
                t[j] = (short)f2bf(xp[j]);
            Af[kc] = t;
        }
        f32x4 acc[4] = {{0,0,0,0},{0,0,0,0},{0,0,0,0},{0,0,0,0}};
#pragma unroll
        for (int kc = 0; kc < 2; ++kc)
#pragma unroll
            for (int cb = 0; cb < 4; ++cb)
                acc[cb] = __builtin_amdgcn_mfma_f32_16x16x32_bf16(Af[kc], Bf[cb][kc], acc[cb], 0, 0, 0);
        float pd[4] = {0,0,0,0}, pb[4] = {0,0,0,0};
#pragma unroll
        for (int cb = 0; cb < 4; ++cb)
#pragma unroll
            for (int r = 0; r < 4; ++r) {
                float val = acc[cb][r] + bl[cb];
                acc[cb][r] = val;
                pd[r] = fmaf(val, dvl[cb], pd[r]);
                pb[r] = fmaf(val, dbl[cb], pb[r]);
            }
#pragma unroll
        for (int o = 1; o < 16; o <<= 1)
#pragma unroll
            for (int r = 0; r < 4; ++r) {
                pd[r] += __shfl_xor(pd[r], o, 64);
                pb[r] += __shfl_xor(pb[r], o, 64);
            }
        int rg = rbase + g * 4;
        if (wv == 3) {
            // state partials: every row is a source (src list = arange)
#pragma unroll
            for (int r = 0; r < 4; ++r) {
                int row = rg + r;
                float e = pd[r] + sdst;
                e = e > 0.f ? e : ALPHA * e;
                float w = (row < N) ? __expf(e) : 0.f;
                pden += w;
#pragma unroll
                for (int cb = 0; cb < 4; ++cb)
                    pnum[cb] = fmaf(w, acc[cb][r], pnum[cb]);
            }
            continue;                          // no global writes for wave 3
        }
        if (li == 0) {
#pragma unroll
            for (int r = 0; r < 4; ++r) {
                int row = rg + r;
                if (row < N) {
                    sm[row] = pd[r];
                    if (wv == 0) sdB[row] = pb[r];
                }
            }
        }
        if (wv == 0) {
#pragma unroll
            for (int r = 0; r < 4; ++r) {
                int row = rg + r;
                if (row < N)
#pragma unroll
                    for (int cb = 0; cb < 4; ++cb)
                        Wh[(long long)row * 64 + cb * 16 + li] = acc[cb][r];
            }
        } else {
#pragma unroll
            for (int r = 0; r < 4; ++r) {
                int row = rg + r;
                if (row < N)
#pragma unroll
                    for (int cb = 0; cb < 4; ++cb)
                        zm[(long long)row * 64 + cb * 16 + li] = f2bf(acc[cb][r]);
            }
        }
    }
    if (wv == 3) {
        // reduce over the 4 row-groups (lanes g=0..3 hold disjoint rows)
#pragma unroll
        for (int o = 16; o <= 32; o <<= 1) {
            pden += __shfl_xor(pden, o, 64);
#pragma unroll
            for (int cb = 0; cb < 4; ++cb)
                pnum[cb] += __shfl_xor(pnum[cb], o, 64);
        }
        if (lane < 16) {                       // g == 0 lanes
#pragma unroll
            for (int cb = 0; cb < 4; ++cb)
                atomicAdd(&num[cb * 16 + li], pnum[cb]);
            if (li == 0) atomicAdd(den, pden);
        }
    }
}

// =============== edge decode ===============
__device__ __forceinline__ void edge_decode(int k,
    const int* __restrict__ s0, const int* __restrict__ d0, int E0,
    const int* __restrict__ s1, const int* __restrict__ d1, int E1,
    const int* __restrict__ s2, const int* __restrict__ d2, int E2,
    const int* __restrict__ s3, const int* __restrict__ d3,
    int& src, int& bin) {
    if (k < E0) { src = s0[k]; bin = 2 * d0[k]; return; }
    k -= E0; if (k < E1) { src = s1[k]; bin = 2 * d1[k] + 1; return; }
    k -= E1; if (k < E2) { src = s2[k]; bin = ABASE + 2 * d2[k]; return; }
    k -= E2; src = s3[k]; bin = ABASE + 2 * d3[k] + 1;
}

// =============== fused front: scatter | xform P | xform A | state_prep ===============
__global__ __launch_bounds__(256) void fused_front(FrontArgs A) {
    __shared__ float smem[64 * XS_LD];         // X tile (xform) / h+base (scatter)
    int bid = blockIdx.x;
    int tid = threadIdx.x;
    if (bid < A.nblk) {
        // ---- scatter role ----
        int* h = (int*)smem;
        int* base = h + NBUCK;
        for (int i = tid; i < NBUCK; i += 256) h[i] = 0;
        __syncthreads();
        int b0 = bid * CH;
        int b1 = min(b0 + CH, A.E_tot);
        int cbin[16], csrc[16];
#pragma unroll
        for (int it = 0; it < 16; ++it) {
            int i = b0 + it * 256 + tid;
            int bin = -1, src = 0;
            if (i < b1)
                edge_decode(i, A.src_p2p, A.dst_p2p, A.E_p2p,
                            A.src_a2p, A.dst_a2p, A.E_a2p,
                            A.src_p2a, A.dst_p2a, A.E_p2a,
                            A.src_a2a, A.dst_a2a, src, bin);
            cbin[it] = bin; csrc[it] = src;
            if (bin >= 0) atomicAdd(&h[bin >> 8], 1);
        }
        __syncthreads();
        for (int i = tid; i < NBUCK; i += 256) {
            int c = h[i];
            base[i] = c ? (i * CAP + atomicAdd(&A.cursor0[i], c)) : 0;
            h[i] = 0;                           // reuse as local cursor
        }
        __syncthreads();
#pragma unroll
        for (int it = 0; it < 16; ++it) {
            int bin = cbin[it];
            if (bin >= 0) {
                int bk = bin >> 8;
                int pos = base[bk] + atomicAdd(&h[bk], 1);
                if (pos < (bk + 1) * CAP)       // capacity guard (never hit)
                    A.ebuf[pos] = csrc[it] | ((bin & 255) << 16);
            }
        }
        return;
    }
    bid -= A.nblk;
    if (bid < GP) {
        xform_body(bid, smem, A.feat_P, NP,
                   A.W_P, A.b_P, A.WhP, A.a_p2p + 64, A.sd_p2p, A.a_a2p + 64, A.sd_a2p,
                   A.W_p2p, A.b_p2p, A.z_p2p, A.a_p2p, A.ss_p2p,
                   A.W_p2a, A.b_p2a, A.z_p2a, A.a_p2a, A.ss_p2a,
                   A.W_p2s, A.b_p2s, A.a_p2s, A.a_p2s + 64,
                   A.feat_S, A.W_in, A.b_in, A.numP, &A.den2[0]);
        return;
    }
    bid -= GP;
    if (bid < GA) {
        xform_body(bid, smem, A.feat_A, NA,
                   A.W_A, A.b_A, A.WhA, A.a_p2a + 64, A.sd_p2a, A.a_a2a + 64, A.sd_a2a,
                   A.W_a2p, A.b_a2p, A.z_a2p, A.a_a2p, A.ss_a2p,
                   A.W_a2a, A.b_a2a, A.z_a2a, A.a_a2a, A.ss_a2a,
                   A.W_a2s, A.b_a2s, A.a_a2s, A.a_a2s + 64,
                   A.feat_S, A.W_in, A.b_in, A.numA, &A.den2[1]);
        return;
    }
    // ---- state_prep role: outS = Wh_in (finalize adds GAT terms later) ----
    if (tid < 64) {
        int c = tid;
        float acc = A.b_in[c];
        for (int k = 0; k < 64; ++k) acc = fmaf(A.feat_S[k], A.W_in[k * 64 + c], acc);
        A.outS[c] = acc;
    }
}

// =============== in-block exclusive scan of 586 bucket counts (clamped to CAP) ===============
__device__ void scan_counts(const int* __restrict__ counts, int* sstart) {
    __shared__ int wtot_sb[4];
    int tid = threadIdx.x, lane = tid & 63, wv = tid >> 6;
    int carry = 0;
    for (int c = 0; c < 3; ++c) {
        int i = c * 256 + tid;
        int v = (i < NBUCK) ? min(counts[i], CAP) : 0;
        int x = v;
#pragma unroll
        for (int o = 1; o < 64; o <<= 1) {
            int y = __shfl_up(x, o, 64);
            if (lane >= o) x += y;
        }
        if (lane == 63) wtot_sb[wv] = x;
        __syncthreads();
        int woff = carry;
        for (int j = 0; j < wv; ++j) woff += wtot_sb[j];
        int ctot = wtot_sb[0] + wtot_sb[1] + wtot_sb[2] + wtot_sb[3];
        if (i < NBUCK) sstart[i] = x + woff - v;
        __syncthreads();
        carry += ctot;
    }
    if (tid == 0) sstart[NBUCK] = carry;       // total
    __syncthreads();
}

// =============== fused mid: fine_sort (packed) | state finalize ===============
__global__ __launch_bounds__(256) void fused_mid(
    const int* __restrict__ ebuf, const int* __restrict__ cursor0,
    int* __restrict__ ssrc, int* __restrict__ offs,
    const float* __restrict__ numP, const float* __restrict__ numA,
    const float* __restrict__ den2, float* __restrict__ outS) {
    int tid = threadIdx.x, lane = tid & 63, wv = tid >> 6;
    if ((int)blockIdx.x >= NBUCK) {
        // ---- finalize: outS = relu(Wh_in + numP/denP + numA/denA) ----
        if (tid < 64)
            outS[tid] = fmaxf(outS[tid] + numP[tid] / den2[0] + numA[tid] / den2[1], 0.f);
        return;
    }
    // ---- fine_sort role: CAP region -> PACKED bin-sorted ssrc + flat offs ----
    __shared__ int sstart[NBUCK + 1];
    __shared__ int lsrc[CAP];
    __shared__ int lcnt[256];
    __shared__ int loff[256];
    __shared__ int lcur[256];
    __shared__ int wtot[4];
    int b = blockIdx.x;
    scan_counts(cursor0, sstart);              // packed bucket starts
    int pstart = sstart[b];                    // packed output base
    int rstart = b * CAP;                      // ebuf region base
    int cnt = min(cursor0[b], CAP);
    lcnt[tid] = 0;
    __syncthreads();
    for (int e = tid; e < cnt; e += 256)
        atomicAdd(&lcnt[((unsigned)ebuf[rstart + e]) >> 16], 1);
    __syncthreads();
    int v = lcnt[tid];
    int x = v;
#pragma unroll
    for (int o = 1; o < 64; o <<= 1) {
        int y = __shfl_up(x, o, 64);
        if (lane >= o) x += y;
    }
    if (lane == 63) wtot[wv] = x;
    __syncthreads();
    int woff = 0;
    for (int j = 0; j < wv; ++j) woff += wtot[j];
    int excl = x + woff - v;
    loff[tid] = excl;
    lcur[tid] = excl;
    __syncthreads();
    for (int e = tid; e < cnt; e += 256) {
        int val = ebuf[rstart + e];
        int pos = atomicAdd(&lcur[((unsigned)val) >> 16], 1);
        lsrc[pos] = val & 0xFFFF;
    }
    __syncthreads();
    for (int i = tid; i < cnt; i += 256) ssrc[pstart + i] = lsrc[i];   // coalesced, packed
    int gb = b * 256 + tid;
    if (gb < NBINS) offs[gb] = pstart + loff[tid];
    if (b == 0 && tid == 0) offs[NBINS] = sstart[NBUCK];
}

// =============== per-segment gather, 8 edges in flight (verbatim R8) ===============
__device__ __forceinline__ void seg_gat_g8(const int* __restrict__ ssrc, int s0, int s1,
                                           const float* __restrict__ ss, float sd,
                                           const u16* __restrict__ z, int lane,
                                           float* __restrict__ acc) {
    int cnt = s1 - s0;
    if (cnt <= 0) return;
    int egrp = lane >> 3, cg8 = (lane & 7) * 8;
    if (cnt <= 64) {                    // fast path (deg <= 64: essentially always)
        int s = 0; float w = 0.f;
        if (lane < cnt) {
            s = ssrc[s0 + lane];        // coalesced
            float e = ss[s] + sd;
            e = e > 0.f ? e : ALPHA * e;
            w = __expf(e);
        }
        float den = w;
#pragma unroll
        for (int o = 32; o > 0; o >>= 1) den += __shfl_xor(den, o, 64);
        w *= 1.f / den;
        int nit = (cnt + 7) >> 3;
        for (int it = 0; it < nit; ++it) {
            int ei = it * 8 + egrp;
            float wt = __shfl(w, ei, 64);   // 0 for ei >= cnt
            int   st = __shfl(s, ei, 64);
            u16x8 q = *(const u16x8*)(z + (long long)st * 64 + cg8);
#pragma unroll
            for (int j = 0; j < 8; ++j)
                acc[j] = fmaf(wt, bf2f(q[j]), acc[j]);
        }
    } else {                            // general path (rare)
        float den = 0.f;
        for (int i = s0 + lane; i < s1; i += 64) {
            float e = ss[ssrc[i]] + sd; e = e > 0.f ? e : ALPHA * e; den += __expf(e);
        }
#pragma unroll
        for (int o = 32; o > 0; o >>= 1) den += __shfl_xor(den, o, 64);
        float inv = 1.f / den;
        for (int c = s0; c < s1; c += 64) {
            int i = c + lane; int s = 0; float w = 0.f;
            if (i < s1) {
                s = ssrc[i];
                float e = ss[s] + sd; e = e > 0.f ? e : ALPHA * e;
                w = __expf(e) * inv;
            }
            int cc = min(64, s1 - c);
            int nit = (cc + 7) >> 3;
            for (int it = 0; it < nit; ++it) {
                int ei = it * 8 + egrp;
                float wt = __shfl(w, ei, 64);
                int   st = __shfl(s, ei, 64);
                u16x8 q = *(const u16x8*)(z + (long long)st * 64 + cg8);
#pragma unroll
                for (int j = 0; j < 8; ++j)
                    acc[j] = fmaf(wt, bf2f(q[j]), acc[j]);
            }
        }
    }
}

// =============== gat_all: PURE kernel (R8-proven) ===============
__global__ __launch_bounds__(256) void gat_all(
    const int* __restrict__ ssrc, const int* __restrict__ offs,
    const float* __restrict__ WhP, float* __restrict__ outP,
    const float* __restrict__ WhA, float* __restrict__ outA,
    const float* __restrict__ ss_p2p, const float* __restrict__ sd_p2p, const u16* __restrict__ z_p2p,
    const float* __restrict__ ss_a2p, const float* __restrict__ sd_a2p, const u16* __restrict__ z_a2p,
    const float* __restrict__ ss_p2a, const float* __restrict__ sd_p2a, const u16* __restrict__ z_p2a,
    const float* __restrict__ ss_a2a, const float* __restrict__ sd_a2a, const u16* __restrict__ z_a2a) {
    int lane = threadIdx.x & 63;
    int g = (blockIdx.x * blockDim.x + threadIdx.x) >> 6;   // wave id = node id
    if (g >= NP + NA) return;                               // wave-uniform
    bool isP = g < NP;
    int d = isP ? g : g - NP;
    int bin0 = isP ? 2 * d : ABASE + 2 * d;
    int e0 = offs[bin0], e1 = offs[bin0 + 1], e2 = offs[bin0 + 2];
    float acc[8] = {0.f, 0.f, 0.f, 0.f, 0.f, 0.f, 0.f, 0.f};
    if (isP) {
        seg_gat_g8(ssrc, e0, e1, ss_p2p, sd_p2p[d], z_p2p, lane, acc);
        seg_gat_g8(ssrc, e1, e2, ss_a2p, sd_a2p[d], z_a2p, lane, acc);
    } else {
        seg_gat_g8(ssrc, e0, e1, ss_p2a, sd_p2a[d], z_p2a, lane, acc);
        seg_gat_g8(ssrc, e1, e2, ss_a2a, sd_a2a[d], z_a2a, lane, acc);
    }
#pragma unroll
    for (int o = 8; o <= 32; o <<= 1)
#pragma unroll
        for (int j = 0; j < 8; ++j)
            acc[j] += __shfl_xor(acc[j], o, 64);
    if (lane < 8) {
        const float* Wh = isP ? WhP : WhA;
        float* outp = isP ? outP : outA;
        const float* sp = &Wh[(long long)d * 64 + lane * 8];
        float4 s0v = *(const float4*)sp;
        float4 s1v = *(const float4*)(sp + 4);
        float4 r0, r1;
        r0.x = fmaxf(s0v.x + acc[0], 0.f); r0.y = fmaxf(s0v.y + acc[1], 0.f);
        r0.z = fmaxf(s0v.z + acc[2], 0.f); r0.w = fmaxf(s0v.w + acc[3], 0.f);
        r1.x = fmaxf(s1v.x + acc[4], 0.f); r1.y = fmaxf(s1v.y + acc[5], 0.f);
        r1.z = fmaxf(s1v.z + acc[6], 0.f); r1.w = fmaxf(s1v.w + acc[7], 0.f);
        float* op = &outp[(long long)d * 64 + lane * 8];
        *(float4*)op = r0;
        *(float4*)(op + 4) = r1;
    }
}

extern "C" void kernel_launch(void* const* d_in, const int* in_sizes, int n_in,
                              void* d_out, int out_size, void* d_ws, size_t ws_size,
                              hipStream_t stream) {
    const float* feat_P = (const float*)d_in[0];
    const float* feat_A = (const float*)d_in[1];
    const float* feat_S = (const float*)d_in[2];
    const float* W_P   = (const float*)d_in[3];  const float* b_P   = (const float*)d_in[4];
    const float* W_A   = (const float*)d_in[5];  const float* b_A   = (const float*)d_in[6];
    const float* W_p2p = (const float*)d_in[7];  const float* b_p2p = (const float*)d_in[8];
    const float* W_p2a = (const float*)d_in[9];  const float* b_p2a = (const float*)d_in[10];
    const float* W_a2p = (const float*)d_in[11]; const float* b_a2p = (const float*)d_in[12];
    const float* W_a2a = (const float*)d_in[13]; const float* b_a2a = (const float*)d_in[14];
    const float* W_p2s = (const float*)d_in[15]; const float* b_p2s = (const float*)d_in[16];
    const float* W_a2s = (const float*)d_in[17]; const float* b_a2s = (const float*)d_in[18];
    const float* W_in  = (const float*)d_in[19]; const float* b_in  = (const float*)d_in[20];
    const float* a_p2p = (const float*)d_in[21];
    const float* a_p2a = (const float*)d_in[22];
    const float* a_a2p = (const float*)d_in[23];
    const float* a_a2a = (const float*)d_in[24];
    const float* a_p2s = (const float*)d_in[25];
    const float* a_a2s = (const float*)d_in[26];
    const int* src_p2p = (const int*)d_in[27]; const int* dst_p2p = (const int*)d_in[28];
    const int* src_p2a = (const int*)d_in[29]; const int* dst_p2a = (const int*)d_in[30];
    const int* src_a2p = (const int*)d_in[31]; const int* dst_a2p = (const int*)d_in[32];
    const int* src_a2a = (const int*)d_in[33]; const int* dst_a2a = (const int*)d_in[34];
    int E_p2p = in_sizes[27], E_p2a = in_sizes[29], E_a2p = in_sizes[31], E_a2a = in_sizes[33];
    int E_tot = E_p2p + E_a2p + E_p2a + E_a2a;

    float* out = (float*)d_out;
    float* outP = out;
    float* outA = out + (long long)NP * 64;
    float* outS = out + (long long)(NP + NA) * 64;

    // ---- workspace layout ----
    float* ws = (float*)d_ws;
    float* WhP = ws; ws += (long long)NP * 64;
    float* WhA = ws; ws += (long long)NA * 64;
    u16* z_p2p = (u16*)ws; ws += (long long)NP * 32;
    u16* z_p2a = (u16*)ws; ws += (long long)NP * 32;
    u16* z_a2p = (u16*)ws; ws += (long long)NA * 32;
    u16* z_a2a = (u16*)ws; ws += (long long)NA * 32;
    float* ss_p2p = ws; ws += NP;  float* sd_p2p = ws; ws += NP;
    float* ss_p2a = ws; ws += NP;  float* sd_p2a = ws; ws += NA;
    float* ss_a2p = ws; ws += NA;  float* sd_a2p = ws; ws += NP;
    float* ss_a2a = ws; ws += NA;  float* sd_a2a = ws; ws += NA;
    // ---- zeroed-every-call region (one tiny memset) ----
    float* zreg = ws;
    int*   cursor0 = (int*)ws; ws += NBUCK;
    float* den2 = ws; ws += 2;
    float* numP = ws; ws += 64;
    float* numA = ws; ws += 64;
    size_t zbytes = (size_t)((char*)ws - (char*)zreg);
    // ---- rest ----
    int* iw = (int*)ws;
    int* ebuf = iw; iw += NBUCK * CAP;     // CAP-strided staging (scatter/sort only)
    int* ssrc = iw; iw += E_tot;           // packed dst-sorted srcs (gat-hot)
    int* offs = iw; iw += NBINS + 1;       // packed flat bin offsets (gat-hot)

    const int T = 256;
    int nblk = (E_tot + CH - 1) / CH;

    hipMemsetAsync(zreg, 0, zbytes, stream);

    // ---- fused front: scatter | xform P | xform A | state_prep ----
    FrontArgs FA;
    FA.feat_P = feat_P; FA.feat_A = feat_A; FA.feat_S = feat_S;
    FA.W_P = W_P; FA.b_P = b_P; FA.W_A = W_A; FA.b_A = b_A;
    FA.W_p2p = W_p2p; FA.b_p2p = b_p2p; FA.W_p2a = W_p2a; FA.b_p2a = b_p2a;
    FA.W_a2p = W_a2p; FA.b_a2p = b_a2p; FA.W_a2a = W_a2a; FA.b_a2a = b_a2a;
    FA.W_p2s = W_p2s; FA.b_p2s = b_p2s; FA.W_a2s = W_a2s; FA.b_a2s = b_a2s;
    FA.W_in = W_in; FA.b_in = b_in;
    FA.a_p2p = a_p2p; FA.a_p2a = a_p2a; FA.a_a2p = a_a2p; FA.a_a2a = a_a2a;
    FA.a_p2s = a_p2s; FA.a_a2s = a_a2s;
    FA.WhP = WhP; FA.WhA = WhA;
    FA.z_p2p = z_p2p; FA.z_p2a = z_p2a;
    FA.z_a2p = z_a2p; FA.z_a2a = z_a2a;
    FA.ss_p2p = ss_p2p; FA.sd_p2p = sd_p2p; FA.ss_p2a = ss_p2a; FA.sd_p2a = sd_p2a;
    FA.ss_a2p = ss_a2p; FA.sd_a2p = sd_a2p; FA.ss_a2a = ss_a2a; FA.sd_a2a = sd_a2a;
    FA.outS = outS; FA.den2 = den2; FA.numP = numP; FA.numA = numA;
    FA.src_p2p = src_p2p; FA.dst_p2p = dst_p2p; FA.src_a2p = src_a2p; FA.dst_a2p = dst_a2p;
    FA.src_p2a = src_p2a; FA.dst_p2a = dst_p2a; FA.src_a2a = src_a2a; FA.dst_a2a = dst_a2a;
    FA.E_p2p = E_p2p; FA.E_a2p = E_a2p; FA.E_p2a = E_p2a; FA.E_a2a = E_a2a;
    FA.E_tot = E_tot; FA.nblk = nblk;
    FA.cursor0 = cursor0; FA.ebuf = ebuf;
    fused_front<<<nblk + GP + GA + 1, T, 0, stream>>>(FA);

    // ---- fused mid: fine_sort (packed) | state finalize ----
    fused_mid<<<NBUCK + 1, T, 0, stream>>>(ebuf, cursor0, ssrc, offs,
                                           numP, numA, den2, outS);

    // ---- gat_all: pure kernel (R8-proven) ----
    gat_all<<<((NP + NA) * 64 + T - 1) / T, T, 0, stream>>>(ssrc, offs,
        WhP, outP, WhA, outA,
        ss_p2p, sd_p2p, z_p2p, ss_a2p, sd_a2p, z_a2p,
        ss_p2a, sd_p2a, z_p2a, ss_a2a, sd_a2a, z_a2a);
}

// Round 16
// 131.567 us; speedup vs baseline: 1.2141x; 1.2141x over previous
//
#include <hip/hip_runtime.h>
#include <math.h>

#define ALPHA 0.2f
#define NP 50000
#define NA 25000
#define NBINS 150000          // P: 2*NP interleaved bins, then A: 2*NA
#define ABASE 100000          // bin base for A nodes
#define NBUCK 586             // ceil(NBINS/256)
#define CH 4096               // edges per scatter block (= 16*256, static unroll)
#define CAP 8192              // fixed bucket region capacity in ebuf (max observed ~3.9k)
#define GP ((NP + 63) / 64)   // 782 xform-P blocks
#define GA ((NA + 63) / 64)   // 391 xform-A blocks
#define SB_P 384              // state-accum blocks for P
#define SB_A 192              // state-accum blocks for A

typedef unsigned short u16;
typedef __attribute__((ext_vector_type(8))) short bf16x8;
typedef __attribute__((ext_vector_type(8))) unsigned short u16x8;
typedef __attribute__((ext_vector_type(4))) float f32x4;

__device__ __forceinline__ float bf2f(u16 u) { return __uint_as_float(((unsigned)u) << 16); }
__device__ __forceinline__ u16 f2bf(float f) {
    unsigned x = __float_as_uint(f);
    return (u16)((x + 0x7fffu + ((x >> 16) & 1u)) >> 16);   // RNE
}

// =============== args ===============
struct K1Args {      // scatter | state-accumulate
    const int *s0, *d0, *s1, *d1, *s2, *d2, *s3, *d3;
    int E0, E1, E2, E3, Etot, nblk;
    int *cursor0, *ebuf;
    const float *feat_P, *feat_A, *feat_S;
    const float *W_p2s, *b_p2s, *a_p2s, *W_a2s, *b_a2s, *a_a2s, *W_in, *b_in;
    float *numP, *numA, *den2;   // num* = raw feature-space numerators (64 each)
};

struct K2Args {      // fine_sort | xform P | xform A | finalize
    const int *ebuf; const int *cursor0;
    int *ssrc; int *offs;
    const float *feat_P, *feat_A, *feat_S;
    const float *W_P, *b_P, *W_A, *b_A, *W_p2p, *b_p2p, *W_p2a, *b_p2a,
                *W_a2p, *b_a2p, *W_a2a, *b_a2a, *W_p2s, *b_p2s, *W_a2s, *b_a2s,
                *W_in, *b_in;
    const float *a_p2p, *a_p2a, *a_a2p, *a_a2a;
    float *WhP, *WhA;
    u16 *z_p2p, *z_p2a, *z_a2p, *z_a2a;
    float *ss_p2p, *sd_p2p, *ss_p2a, *sd_p2a, *ss_a2p, *sd_a2p, *ss_a2a, *sd_a2a;
    const float *numP, *numA, *den2;
    float *outS;
};

// =============== edge decode ===============
__device__ __forceinline__ void edge_decode(int k,
    const int* __restrict__ s0, const int* __restrict__ d0, int E0,
    const int* __restrict__ s1, const int* __restrict__ d1, int E1,
    const int* __restrict__ s2, const int* __restrict__ d2, int E2,
    const int* __restrict__ s3, const int* __restrict__ d3,
    int& src, int& bin) {
    if (k < E0) { src = s0[k]; bin = 2 * d0[k]; return; }
    k -= E0; if (k < E1) { src = s1[k]; bin = 2 * d1[k] + 1; return; }
    k -= E1; if (k < E2) { src = s2[k]; bin = ABASE + 2 * d2[k]; return; }
    k -= E2; src = s3[k]; bin = ABASE + 2 * d3[k] + 1;
}

// =============== k1: scatter | state-accumulate (feature-space, linearity trick) ===============
__global__ __launch_bounds__(256) void k1_kernel(K1Args A) {
    __shared__ int h[NBUCK];
    __shared__ int base[NBUCK];
    int bid = blockIdx.x;
    int tid = threadIdx.x;
    if (bid < A.nblk) {
        // ---- scatter role: window reservation into fixed bucket regions ----
        for (int i = tid; i < NBUCK; i += 256) h[i] = 0;
        __syncthreads();
        int b0 = bid * CH;
        int b1 = min(b0 + CH, A.Etot);
        int cbin[16], csrc[16];
#pragma unroll
        for (int it = 0; it < 16; ++it) {
            int i = b0 + it * 256 + tid;
            int bin = -1, src = 0;
            if (i < b1)
                edge_decode(i, A.s0, A.d0, A.E0, A.s1, A.d1, A.E1,
                            A.s2, A.d2, A.E2, A.s3, A.d3, src, bin);
            cbin[it] = bin; csrc[it] = src;
            if (bin >= 0) atomicAdd(&h[bin >> 8], 1);
        }
        __syncthreads();
        for (int i = tid; i < NBUCK; i += 256) {
            int c = h[i];
            base[i] = c ? (i * CAP + atomicAdd(&A.cursor0[i], c)) : 0;
            h[i] = 0;                           // reuse as local cursor
        }
        __syncthreads();
#pragma unroll
        for (int it = 0; it < 16; ++it) {
            int bin = cbin[it];
            if (bin >= 0) {
                int bk = bin >> 8;
                int pos = base[bk] + atomicAdd(&h[bk], 1);
                if (pos < (bk + 1) * CAP)       // capacity guard (never hit)
                    A.ebuf[pos] = csrc[it] | ((bin & 255) << 16);
            }
        }
        return;
    }
    // ---- state-accumulate role: num_raw += w*x, den += w over ALL nodes ----
    float* red = (float*)h;                     // reuse LDS: [4][64] partials + [4] den
    int sb = bid - A.nblk;
    bool isP = sb < SB_P;
    int bidl = isP ? sb : sb - SB_P;
    int nb = isP ? SB_P : SB_A;
    int N = isP ? NP : NA;
    const float* X   = isP ? A.feat_P : A.feat_A;
    const float* W   = isP ? A.W_p2s  : A.W_a2s;
    const float* b   = isP ? A.b_p2s  : A.b_a2s;
    const float* a   = isP ? A.a_p2s  : A.a_a2s;   // [128]: src-half then dst-half
    float* num       = isP ? A.numP   : A.numA;
    float* den       = isP ? &A.den2[0] : &A.den2[1];
    int lane = tid & 63, wv = tid >> 6;
    // v[lane] = dot(W row lane, a_src)  (contiguous row read)
    float v = 0.f;
    for (int c = 0; c < 64; ++c) v = fmaf(W[lane * 64 + c], a[c], v);
    // c0 = dot(b, a_src); sdst = dot(Wh_in, a_dst)
    float t0 = b[lane] * a[lane];
    float whc = A.b_in[lane];
    for (int k = 0; k < 64; ++k) whc = fmaf(A.feat_S[k], A.W_in[k * 64 + lane], whc);
    float t1 = whc * a[64 + lane];
#pragma unroll
    for (int o = 1; o < 64; o <<= 1) {
        t0 += __shfl_xor(t0, o, 64);
        t1 += __shfl_xor(t1, o, 64);
    }
    float cbias = t0 + t1;                      // c0 + sdst
    float accx = 0.f, accd = 0.f;
    int gw = bidl * 4 + wv, waves = nb * 4;
    for (int r = gw; r < N; r += waves) {
        float x = X[(long long)r * 64 + lane];  // coalesced
        float ss = x * v;
#pragma unroll
        for (int o = 1; o < 64; o <<= 1) ss += __shfl_xor(ss, o, 64);
        float e = ss + cbias;
        e = e > 0.f ? e : ALPHA * e;
        float w = __expf(e);
        accx = fmaf(w, x, accx);
        accd += w;
    }
    red[wv * 64 + lane] = accx;
    if (lane == 0) red[256 + wv] = accd;
    __syncthreads();
    if (tid < 64) {
        float t = red[tid] + red[64 + tid] + red[128 + tid] + red[192 + tid];
        atomicAdd(&num[tid], t);
    }
    if (tid == 64) atomicAdd(den, red[256] + red[257] + red[258] + red[259]);
}

// =============== in-block exclusive scan of 586 bucket counts (clamped to CAP) ===============
__device__ void scan_counts(const int* __restrict__ counts, int* sstart) {
    __shared__ int wtot_sb[4];
    int tid = threadIdx.x, lane = tid & 63, wv = tid >> 6;
    int carry = 0;
    for (int c = 0; c < 3; ++c) {
        int i = c * 256 + tid;
        int v = (i < NBUCK) ? min(counts[i], CAP) : 0;
        int x = v;
#pragma unroll
        for (int o = 1; o < 64; o <<= 1) {
            int y = __shfl_up(x, o, 64);
            if (lane >= o) x += y;
        }
        if (lane == 63) wtot_sb[wv] = x;
        __syncthreads();
        int woff = carry;
        for (int j = 0; j < wv; ++j) woff += wtot_sb[j];
        int ctot = wtot_sb[0] + wtot_sb[1] + wtot_sb[2] + wtot_sb[3];
        if (i < NBUCK) sstart[i] = x + woff - v;
        __syncthreads();
        carry += ctot;
    }
    if (tid == 0) sstart[NBUCK] = carry;
    __syncthreads();
}

// =============== MFMA 3-matrix transform (waves 0-2; wave 3 exits) ===============
__device__ __forceinline__ void xform_body3(int bid,
    const float* __restrict__ X, int N,
    const float* __restrict__ W0, const float* __restrict__ b0, float* __restrict__ Wh,
    const float* __restrict__ dA, float* __restrict__ sdA,
    const float* __restrict__ dB, float* __restrict__ sdB,
    const float* __restrict__ W1, const float* __restrict__ b1, u16* __restrict__ z1,
    const float* __restrict__ v1, float* __restrict__ s1,
    const float* __restrict__ W2, const float* __restrict__ b2, u16* __restrict__ z2,
    const float* __restrict__ v2, float* __restrict__ s2)
{
    int tid = threadIdx.x, wv = tid >> 6, lane = tid & 63;
    if (wv == 3) return;                        // 3 matrices only
    int g = lane >> 4, li = lane & 15;
    const float* Wm = wv == 0 ? W0 : wv == 1 ? W1 : W2;
    const float* bm = wv == 0 ? b0 : wv == 1 ? b1 : b2;
    const float* dv = wv == 0 ? dA : wv == 1 ? v1 : v2;
    float* sm       = wv == 0 ? sdA : wv == 1 ? s1 : s2;
    u16* zm         = wv == 1 ? z1 : wv == 2 ? z2 : nullptr;

    bf16x8 Bf[4][2];
#pragma unroll
    for (int cb = 0; cb < 4; ++cb)
#pragma unroll
        for (int kc = 0; kc < 2; ++kc) {
            bf16x8 t;
#pragma unroll
            for (int j = 0; j < 8; ++j)
                t[j] = (short)f2bf(Wm[(kc * 32 + g * 8 + j) * 64 + cb * 16 + li]);
            Bf[cb][kc] = t;
        }
    float bl[4], dvl[4], dbl[4];
#pragma unroll
    for (int cb = 0; cb < 4; ++cb) {
        bl[cb]  = bm[cb * 16 + li];
        dvl[cb] = dv[cb * 16 + li];
        dbl[cb] = (wv == 0) ? dB[cb * 16 + li] : 0.f;
    }
    int base0 = bid * 64;
#pragma unroll
    for (int rt = 0; rt < 4; ++rt) {
        int rbase = base0 + rt * 16;
        if (rbase >= N) break;
        int rowC = min(rbase + li, N - 1);
        bf16x8 Af[2];
#pragma unroll
        for (int kc = 0; kc < 2; ++kc) {
            const float* xp = X + (long long)rowC * 64 + kc * 32 + g * 8;
            float4 x0 = *(const float4*)xp;
            float4 x1 = *(const float4*)(xp + 4);
            bf16x8 t;
            t[0] = (short)f2bf(x0.x); t[1] = (short)f2bf(x0.y);
            t[2] = (short)f2bf(x0.z); t[3] = (short)f2bf(x0.w);
            t[4] = (short)f2bf(x1.x); t[5] = (short)f2bf(x1.y);
            t[6] = (short)f2bf(x1.z); t[7] = (short)f2bf(x1.w);
            Af[kc] = t;
        }
        f32x4 acc[4] = {{0,0,0,0},{0,0,0,0},{0,0,0,0},{0,0,0,0}};
#pragma unroll
        for (int kc = 0; kc < 2; ++kc)
#pragma unroll
            for (int cb = 0; cb < 4; ++cb)
                acc[cb] = __builtin_amdgcn_mfma_f32_16x16x32_bf16(Af[kc], Bf[cb][kc], acc[cb], 0, 0, 0);
        float pd[4] = {0,0,0,0}, pb[4] = {0,0,0,0};
#pragma unroll
        for (int cb = 0; cb < 4; ++cb)
#pragma unroll
            for (int r = 0; r < 4; ++r) {
                float val = acc[cb][r] + bl[cb];
                acc[cb][r] = val;
                pd[r] = fmaf(val, dvl[cb], pd[r]);
                pb[r] = fmaf(val, dbl[cb], pb[r]);
            }
#pragma unroll
        for (int o = 1; o < 16; o <<= 1)
#pragma unroll
            for (int r = 0; r < 4; ++r) {
                pd[r] += __shfl_xor(pd[r], o, 64);
                pb[r] += __shfl_xor(pb[r], o, 64);
            }
        int rg = rbase + g * 4;
        if (li == 0) {
#pragma unroll
            for (int r = 0; r < 4; ++r) {
                int row = rg + r;
                if (row < N) {
                    sm[row] = pd[r];
                    if (wv == 0) sdB[row] = pb[r];
                }
            }
        }
        if (wv == 0) {
#pragma unroll
            for (int r = 0; r < 4; ++r) {
                int row = rg + r;
                if (row < N)
#pragma unroll
                    for (int cb = 0; cb < 4; ++cb)
                        Wh[(long long)row * 64 + cb * 16 + li] = acc[cb][r];
            }
        } else {
#pragma unroll
            for (int r = 0; r < 4; ++r) {
                int row = rg + r;
                if (row < N)
#pragma unroll
                    for (int cb = 0; cb < 4; ++cb)
                        zm[(long long)row * 64 + cb * 16 + li] = f2bf(acc[cb][r]);
            }
        }
    }
}

// =============== k2: fine_sort | xform P | xform A | state finalize ===============
__global__ __launch_bounds__(256) void k2_kernel(K2Args A) {
    __shared__ int smem_i[NBUCK + 1 + 768 + 4];     // sstart | lcnt | loff | lcur | wtot
    __shared__ u16 lsrc[CAP];
    int bid = blockIdx.x;
    int tid = threadIdx.x, lane = tid & 63, wv = tid >> 6;
    if (bid < NBUCK) {
        // ---- fine_sort role: CAP region -> PACKED bin-sorted ssrc + flat offs ----
        int* sstart = smem_i;
        int* lcnt = smem_i + NBUCK + 1;
        int* loff = lcnt + 256;
        int* lcur = loff + 256;
        int* wtot = lcur + 256;
        int b = bid;
        scan_counts(A.cursor0, sstart);
        int pstart = sstart[b];
        int rstart = b * CAP;
        int cnt = min(A.cursor0[b], CAP);
        lcnt[tid] = 0;
        __syncthreads();
        for (int e = tid; e < cnt; e += 256)
            atomicAdd(&lcnt[((unsigned)A.ebuf[rstart + e]) >> 16], 1);
        __syncthreads();
        int v = lcnt[tid];
        int x = v;
#pragma unroll
        for (int o = 1; o < 64; o <<= 1) {
            int y = __shfl_up(x, o, 64);
            if (lane >= o) x += y;
        }
        if (lane == 63) wtot[wv] = x;
        __syncthreads();
        int woff = 0;
        for (int j = 0; j < wv; ++j) woff += wtot[j];
        int excl = x + woff - v;
        loff[tid] = excl;
        lcur[tid] = excl;
        __syncthreads();
        for (int e = tid; e < cnt; e += 256) {
            int val = A.ebuf[rstart + e];
            int pos = atomicAdd(&lcur[((unsigned)val) >> 16], 1);
            lsrc[pos] = (u16)(val & 0xFFFF);
        }
        __syncthreads();
        for (int i = tid; i < cnt; i += 256) A.ssrc[pstart + i] = (int)lsrc[i];
        int gb = b * 256 + tid;
        if (gb < NBINS) A.offs[gb] = pstart + loff[tid];
        if (b == 0 && tid == 0) A.offs[NBINS] = sstart[NBUCK];
        return;
    }
    bid -= NBUCK;
    if (bid < GP) {
        xform_body3(bid, A.feat_P, NP,
                    A.W_P, A.b_P, A.WhP, A.a_p2p + 64, A.sd_p2p, A.a_a2p + 64, A.sd_a2p,
                    A.W_p2p, A.b_p2p, A.z_p2p, A.a_p2p, A.ss_p2p,
                    A.W_p2a, A.b_p2a, A.z_p2a, A.a_p2a, A.ss_p2a);
        return;
    }
    bid -= GP;
    if (bid < GA) {
        xform_body3(bid, A.feat_A, NA,
                    A.W_A, A.b_A, A.WhA, A.a_p2a + 64, A.sd_p2a, A.a_a2a + 64, A.sd_a2a,
                    A.W_a2p, A.b_a2p, A.z_a2p, A.a_a2p, A.ss_a2p,
                    A.W_a2a, A.b_a2a, A.z_a2a, A.a_a2a, A.ss_a2a);
        return;
    }
    // ---- finalize role: outS = relu(Wh_in + (numP@W_p2s)/denP + b_p2s + (numA@W_a2s)/denA + b_a2s)
    if (tid < 64) {
        int c = tid;
        float whc = A.b_in[c];
        for (int k = 0; k < 64; ++k) whc = fmaf(A.feat_S[k], A.W_in[k * 64 + c], whc);
        float mp = 0.f, ma = 0.f;
        for (int k = 0; k < 64; ++k) {
            mp = fmaf(A.numP[k], A.W_p2s[k * 64 + c], mp);
            ma = fmaf(A.numA[k], A.W_a2s[k * 64 + c], ma);
        }
        float r = whc + mp / A.den2[0] + A.b_p2s[c] + ma / A.den2[1] + A.b_a2s[c];
        A.outS[c] = fmaxf(r, 0.f);
    }
}

// =============== per-segment gather, 8 edges in flight (verbatim R8) ===============
__device__ __forceinline__ void seg_gat_g8(const int* __restrict__ ssrc, int s0, int s1,
                                           const float* __restrict__ ss, float sd,
                                           const u16* __restrict__ z, int lane,
                                           float* __restrict__ acc) {
    int cnt = s1 - s0;
    if (cnt <= 0) return;
    int egrp = lane >> 3, cg8 = (lane & 7) * 8;
    if (cnt <= 64) {                    // fast path (deg <= 64: essentially always)
        int s = 0; float w = 0.f;
        if (lane < cnt) {
            s = ssrc[s0 + lane];        // coalesced
            float e = ss[s] + sd;
            e = e > 0.f ? e : ALPHA * e;
            w = __expf(e);
        }
        float den = w;
#pragma unroll
        for (int o = 32; o > 0; o >>= 1) den += __shfl_xor(den, o, 64);
        w *= 1.f / den;
        int nit = (cnt + 7) >> 3;
        for (int it = 0; it < nit; ++it) {
            int ei = it * 8 + egrp;
            float wt = __shfl(w, ei, 64);   // 0 for ei >= cnt
            int   st = __shfl(s, ei, 64);
            u16x8 q = *(const u16x8*)(z + (long long)st * 64 + cg8);
#pragma unroll
            for (int j = 0; j < 8; ++j)
                acc[j] = fmaf(wt, bf2f(q[j]), acc[j]);
        }
    } else {                            // general path (rare)
        float den = 0.f;
        for (int i = s0 + lane; i < s1; i += 64) {
            float e = ss[ssrc[i]] + sd; e = e > 0.f ? e : ALPHA * e; den += __expf(e);
        }
#pragma unroll
        for (int o = 32; o > 0; o >>= 1) den += __shfl_xor(den, o, 64);
        float inv = 1.f / den;
        for (int c = s0; c < s1; c += 64) {
            int i = c + lane; int s = 0; float w = 0.f;
            if (i < s1) {
                s = ssrc[i];
                float e = ss[s] + sd; e = e > 0.f ? e : ALPHA * e;
                w = __expf(e) * inv;
            }
            int cc = min(64, s1 - c);
            int nit = (cc + 7) >> 3;
            for (int it = 0; it < nit; ++it) {
                int ei = it * 8 + egrp;
                float wt = __shfl(w, ei, 64);
                int   st = __shfl(s, ei, 64);
                u16x8 q = *(const u16x8*)(z + (long long)st * 64 + cg8);
#pragma unroll
                for (int j = 0; j < 8; ++j)
                    acc[j] = fmaf(wt, bf2f(q[j]), acc[j]);
            }
        }
    }
}

// =============== gat_all: PURE kernel (R8-proven) ===============
__global__ __launch_bounds__(256) void gat_all(
    const int* __restrict__ ssrc, const int* __restrict__ offs,
    const float* __restrict__ WhP, float* __restrict__ outP,
    const float* __restrict__ WhA, float* __restrict__ outA,
    const float* __restrict__ ss_p2p, const float* __restrict__ sd_p2p, const u16* __restrict__ z_p2p,
    const float* __restrict__ ss_a2p, const float* __restrict__ sd_a2p, const u16* __restrict__ z_a2p,
    const float* __restrict__ ss_p2a, const float* __restrict__ sd_p2a, const u16* __restrict__ z_p2a,
    const float* __restrict__ ss_a2a, const float* __restrict__ sd_a2a, const u16* __restrict__ z_a2a) {
    int lane = threadIdx.x & 63;
    int g = (blockIdx.x * blockDim.x + threadIdx.x) >> 6;   // wave id = node id
    if (g >= NP + NA) return;                               // wave-uniform
    bool isP = g < NP;
    int d = isP ? g : g - NP;
    int bin0 = isP ? 2 * d : ABASE + 2 * d;
    int e0 = offs[bin0], e1 = offs[bin0 + 1], e2 = offs[bin0 + 2];
    float acc[8] = {0.f, 0.f, 0.f, 0.f, 0.f, 0.f, 0.f, 0.f};
    if (isP) {
        seg_gat_g8(ssrc, e0, e1, ss_p2p, sd_p2p[d], z_p2p, lane, acc);
        seg_gat_g8(ssrc, e1, e2, ss_a2p, sd_a2p[d], z_a2p, lane, acc);
    } else {
        seg_gat_g8(ssrc, e0, e1, ss_p2a, sd_p2a[d], z_p2a, lane, acc);
        seg_gat_g8(ssrc, e1, e2, ss_a2a, sd_a2a[d], z_a2a, lane, acc);
    }
#pragma unroll
    for (int o = 8; o <= 32; o <<= 1)
#pragma unroll
        for (int j = 0; j < 8; ++j)
            acc[j] += __shfl_xor(acc[j], o, 64);
    if (lane < 8) {
        const float* Wh = isP ? WhP : WhA;
        float* outp = isP ? outP : outA;
        const float* sp = &Wh[(long long)d * 64 + lane * 8];
        float4 s0v = *(const float4*)sp;
        float4 s1v = *(const float4*)(sp + 4);
        float4 r0, r1;
        r0.x = fmaxf(s0v.x + acc[0], 0.f); r0.y = fmaxf(s0v.y + acc[1], 0.f);
        r0.z = fmaxf(s0v.z + acc[2], 0.f); r0.w = fmaxf(s0v.w + acc[3], 0.f);
        r1.x = fmaxf(s1v.x + acc[4], 0.f); r1.y = fmaxf(s1v.y + acc[5], 0.f);
        r1.z = fmaxf(s1v.z + acc[6], 0.f); r1.w = fmaxf(s1v.w + acc[7], 0.f);
        float* op = &outp[(long long)d * 64 + lane * 8];
        *(float4*)op = r0;
        *(float4*)(op + 4) = r1;
    }
}

extern "C" void kernel_launch(void* const* d_in, const int* in_sizes, int n_in,
                              void* d_out, int out_size, void* d_ws, size_t ws_size,
                              hipStream_t stream) {
    const float* feat_P = (const float*)d_in[0];
    const float* feat_A = (const float*)d_in[1];
    const float* feat_S = (const float*)d_in[2];
    const float* W_P   = (const float*)d_in[3];  const float* b_P   = (const float*)d_in[4];
    const float* W_A   = (const float*)d_in[5];  const float* b_A   = (const float*)d_in[6];
    const float* W_p2p = (const float*)d_in[7];  const float* b_p2p = (const float*)d_in[8];
    const float* W_p2a = (const float*)d_in[9];  const float* b_p2a = (const float*)d_in[10];
    const float* W_a2p = (const float*)d_in[11]; const float* b_a2p = (const float*)d_in[12];
    const float* W_a2a = (const float*)d_in[13]; const float* b_a2a = (const float*)d_in[14];
    const float* W_p2s = (const float*)d_in[15]; const float* b_p2s = (const float*)d_in[16];
    const float* W_a2s = (const float*)d_in[17]; const float* b_a2s = (const float*)d_in[18];
    const float* W_in  = (const float*)d_in[19]; const float* b_in  = (const float*)d_in[20];
    const float* a_p2p = (const float*)d_in[21];
    const float* a_p2a = (const float*)d_in[22];
    const float* a_a2p = (const float*)d_in[23];
    const float* a_a2a = (const float*)d_in[24];
    const float* a_p2s = (const float*)d_in[25];
    const float* a_a2s = (const float*)d_in[26];
    const int* src_p2p = (const int*)d_in[27]; const int* dst_p2p = (const int*)d_in[28];
    const int* src_p2a = (const int*)d_in[29]; const int* dst_p2a = (const int*)d_in[30];
    const int* src_a2p = (const int*)d_in[31]; const int* dst_a2p = (const int*)d_in[32];
    const int* src_a2a = (const int*)d_in[33]; const int* dst_a2a = (const int*)d_in[34];
    int E_p2p = in_sizes[27], E_p2a = in_sizes[29], E_a2p = in_sizes[31], E_a2a = in_sizes[33];
    int E_tot = E_p2p + E_a2p + E_p2a + E_a2a;

    float* out = (float*)d_out;
    float* outP = out;
    float* outA = out + (long long)NP * 64;
    float* outS = out + (long long)(NP + NA) * 64;

    // ---- workspace layout ----
    float* ws = (float*)d_ws;
    float* WhP = ws; ws += (long long)NP * 64;
    float* WhA = ws; ws += (long long)NA * 64;
    u16* z_p2p = (u16*)ws; ws += (long long)NP * 32;
    u16* z_p2a = (u16*)ws; ws += (long long)NP * 32;
    u16* z_a2p = (u16*)ws; ws += (long long)NA * 32;
    u16* z_a2a = (u16*)ws; ws += (long long)NA * 32;
    float* ss_p2p = ws; ws += NP;  float* sd_p2p = ws; ws += NP;
    float* ss_p2a = ws; ws += NP;  float* sd_p2a = ws; ws += NA;
    float* ss_a2p = ws; ws += NA;  float* sd_a2p = ws; ws += NP;
    float* ss_a2a = ws; ws += NA;  float* sd_a2a = ws; ws += NA;
    // ---- zeroed-every-call region (one tiny memset) ----
    float* zreg = ws;
    int*   cursor0 = (int*)ws; ws += NBUCK;
    float* den2 = ws; ws += 2;
    float* numP = ws; ws += 64;       // raw feature-space numerators
    float* numA = ws; ws += 64;
    size_t zbytes = (size_t)((char*)ws - (char*)zreg);
    // ---- rest ----
    int* iw = (int*)ws;
    int* ebuf = iw; iw += NBUCK * CAP;
    int* ssrc = iw; iw += E_tot;
    int* offs = iw; iw += NBINS + 1;

    const int T = 256;
    int nblk = (E_tot + CH - 1) / CH;

    hipMemsetAsync(zreg, 0, zbytes, stream);

    // ---- k1: scatter | state-accumulate ----
    K1Args K1;
    K1.s0 = src_p2p; K1.d0 = dst_p2p; K1.s1 = src_a2p; K1.d1 = dst_a2p;
    K1.s2 = src_p2a; K1.d2 = dst_p2a; K1.s3 = src_a2a; K1.d3 = dst_a2a;
    K1.E0 = E_p2p; K1.E1 = E_a2p; K1.E2 = E_p2a; K1.E3 = E_a2a;
    K1.Etot = E_tot; K1.nblk = nblk;
    K1.cursor0 = cursor0; K1.ebuf = ebuf;
    K1.feat_P = feat_P; K1.feat_A = feat_A; K1.feat_S = feat_S;
    K1.W_p2s = W_p2s; K1.b_p2s = b_p2s; K1.a_p2s = a_p2s;
    K1.W_a2s = W_a2s; K1.b_a2s = b_a2s; K1.a_a2s = a_a2s;
    K1.W_in = W_in; K1.b_in = b_in;
    K1.numP = numP; K1.numA = numA; K1.den2 = den2;
    k1_kernel<<<nblk + SB_P + SB_A, T, 0, stream>>>(K1);

    // ---- k2: fine_sort | xform P | xform A | finalize ----
    K2Args K2;
    K2.ebuf = ebuf; K2.cursor0 = cursor0; K2.ssrc = ssrc; K2.offs = offs;
    K2.feat_P = feat_P; K2.feat_A = feat_A; K2.feat_S = feat_S;
    K2.W_P = W_P; K2.b_P = b_P; K2.W_A = W_A; K2.b_A = b_A;
    K2.W_p2p = W_p2p; K2.b_p2p = b_p2p; K2.W_p2a = W_p2a; K2.b_p2a = b_p2a;
    K2.W_a2p = W_a2p; K2.b_a2p = b_a2p; K2.W_a2a = W_a2a; K2.b_a2a = b_a2a;
    K2.W_p2s = W_p2s; K2.b_p2s = b_p2s; K2.W_a2s = W_a2s; K2.b_a2s = b_a2s;
    K2.W_in = W_in; K2.b_in = b_in;
    K2.a_p2p = a_p2p; K2.a_p2a = a_p2a; K2.a_a2p = a_a2p; K2.a_a2a = a_a2a;
    K2.WhP = WhP; K2.WhA = WhA;
    K2.z_p2p = z_p2p; K2.z_p2a = z_p2a; K2.z_a2p = z_a2p; K2.z_a2a = z_a2a;
    K2.ss_p2p = ss_p2p; K2.sd_p2p = sd_p2p; K2.ss_p2a = ss_p2a; K2.sd_p2a = sd_p2a;
    K2.ss_a2p = ss_a2p; K2.sd_a2p = sd_a2p; K2.ss_a2a = ss_a2a; K2.sd_a2a = sd_a2a;
    K2.numP = numP; K2.numA = numA; K2.den2 = den2; K2.outS = outS;
    k2_kernel<<<NBUCK + GP + GA + 1, T, 0, stream>>>(K2);

    // ---- k3: gat_all pure ----
    gat_all<<<((NP + NA) * 64 + T - 1) / T, T, 0, stream>>>(ssrc, offs,
        WhP, outP, WhA, outA,
        ss_p2p, sd_p2p, z_p2p, ss_a2p, sd_a2p, z_a2p,
        ss_p2a, sd_p2a, z_p2a, ss_a2a, sd_a2a, z_a2a);
}